// Round 4
// baseline (218.481 us; speedup 1.0000x reference)
//
#include <hip/hip_runtime.h>
#include <math.h>

typedef __bf16 bf16;
typedef __attribute__((ext_vector_type(8))) __bf16 bf16x8;
typedef __attribute__((ext_vector_type(4))) float f32x4;

#define B_SZ 2
#define T_SZ 1024
#define DM_SZ 1024
#define H_SZ 16
#define D_SZ 64
#define L_SZ 12
#define M_ROWS 2048      // B*T
#define N_QKV 3072

__device__ __forceinline__ f32x4 mfma_16x16x32(bf16x8 a, bf16x8 b, f32x4 c) {
  return __builtin_amdgcn_mfma_f32_16x16x32_bf16(a, b, c, 0, 0, 0);
}

// async global->LDS, 16B per lane. LDS dest semantics: wave-uniform base +
// lane*16 — LDS layout must be contiguous in lane order (no padding).
__device__ __forceinline__ void gload_lds16(const bf16* g, bf16* l) {
  __builtin_amdgcn_global_load_lds((const __attribute__((address_space(1))) void*)g,
                                   (__attribute__((address_space(3))) void*)l,
                                   16, 0, 0);
}

// ---------------------------------------------------------------------------
// fp32 -> bf16 flat cast (x: 2048x1024)
// ---------------------------------------------------------------------------
__global__ __launch_bounds__(256) void k_cast(const float* __restrict__ in,
                                              bf16* __restrict__ out) {
  const int idx = blockIdx.x * 256 + threadIdx.x;  // per 8 elements
  const float* p = in + (size_t)idx * 8;
  f32x4 a = *(const f32x4*)p;
  f32x4 b = *(const f32x4*)(p + 4);
  bf16x8 o;
#pragma unroll
  for (int e = 0; e < 4; ++e) { o[e] = (bf16)a[e]; o[e + 4] = (bf16)b[e]; }
  *(bf16x8*)(out + (size_t)idx * 8) = o;
}

// ---------------------------------------------------------------------------
// fp32 weight transpose + cast, 5 matrices in one launch (z selects).
// z<4: 1024x1024. z=4: 1024x192 (lw).
// ---------------------------------------------------------------------------
__global__ __launch_bounds__(256) void k_transpose5(
    const float* __restrict__ in0, bf16* __restrict__ out0,
    const float* __restrict__ in1, bf16* __restrict__ out1,
    const float* __restrict__ in2, bf16* __restrict__ out2,
    const float* __restrict__ in3, bf16* __restrict__ out3,
    const float* __restrict__ in4, bf16* __restrict__ out4) {
  __shared__ __align__(16) bf16 tile[64][66];
  const int z = blockIdx.z;
  const float* in; bf16* out; int C = 1024;
  if (z == 0)      { in = in0; out = out0; }
  else if (z == 1) { in = in1; out = out1; }
  else if (z == 2) { in = in2; out = out2; }
  else if (z == 3) { in = in3; out = out3; }
  else             { in = in4; out = out4; C = 192; if (blockIdx.x >= 3) return; }
  const int R = 1024;
  const int tc = blockIdx.x * 64;
  const int tr = blockIdx.y * 64;
  const int t = threadIdx.x;
  const int r = t >> 2;
  const int c4 = (t & 3) << 4;
  const float* src = in + (size_t)(tr + r) * C + tc + c4;
  f32x4 f0 = *(const f32x4*)(src);
  f32x4 f1 = *(const f32x4*)(src + 4);
  f32x4 f2 = *(const f32x4*)(src + 8);
  f32x4 f3 = *(const f32x4*)(src + 12);
#pragma unroll
  for (int e = 0; e < 4; ++e) {
    tile[r][c4 + e]      = (bf16)f0[e];
    tile[r][c4 + 4 + e]  = (bf16)f1[e];
    tile[r][c4 + 8 + e]  = (bf16)f2[e];
    tile[r][c4 + 12 + e] = (bf16)f3[e];
  }
  __syncthreads();
  bf16x8 w0, w1;
#pragma unroll
  for (int e = 0; e < 8; ++e) { w0[e] = tile[c4 + e][r]; w1[e] = tile[c4 + 8 + e][r]; }
  bf16* dst = out + (size_t)(tc + r) * R + tr + c4;
  *(bf16x8*)(dst) = w0;
  *(bf16x8*)(dst + 8) = w1;
}

// ---------------------------------------------------------------------------
// V transpose (bf16): V[b][t][h*64+d] -> VTg[(b*16+h)*64+d][t]
// ---------------------------------------------------------------------------
__global__ __launch_bounds__(256) void k_vtrans(const bf16* __restrict__ V,
                                                bf16* __restrict__ VTg) {
  __shared__ __align__(16) bf16 tile[64][66];
  const int tt = blockIdx.x;
  const int bh = blockIdx.y;
  const int b = bh >> 4, h = bh & 15;
  const int t0 = tt * 64;
  const int t = threadIdx.x;
  const int r = t >> 2;
  const int c4 = (t & 3) << 4;
  const bf16* src = V + (size_t)(b * T_SZ + t0 + r) * DM_SZ + h * 64 + c4;
  bf16x8 v0 = *(const bf16x8*)(src);
  bf16x8 v1 = *(const bf16x8*)(src + 8);
#pragma unroll
  for (int e = 0; e < 8; ++e) { tile[r][c4 + e] = v0[e]; tile[r][c4 + 8 + e] = v1[e]; }
  __syncthreads();
  bf16x8 w0, w1;
#pragma unroll
  for (int e = 0; e < 8; ++e) { w0[e] = tile[c4 + e][r]; w1[e] = tile[c4 + 8 + e][r]; }
  bf16* dst = VTg + ((size_t)bh * 64 + r) * T_SZ + t0 + c4;
  *(bf16x8*)(dst) = w0;
  *(bf16x8*)(dst + 8) = w1;
}

// ---------------------------------------------------------------------------
// m97-style GEMM: tile TM x 128, BK=64, global_load_lds staging (no padding).
// 4 waves in 2x2: wave = (TM/2) rows x 64 cols of 16x16 frags.
// EPI 0: QKV epilogue (seg phi->Qp/Kp, plain->V). EPI 1: fp32 out + bias.
// ---------------------------------------------------------------------------
template <int TM, int EPI>
__global__ __launch_bounds__(256) void k_gemm128(
    const bf16* __restrict__ A, const bf16* __restrict__ Wt,
    const float* __restrict__ qb, const float* __restrict__ kb,
    const float* __restrict__ vb,
    bf16* __restrict__ Qp, bf16* __restrict__ Kp, bf16* __restrict__ V,
    float* __restrict__ outF) {
  constexpr int MI = TM / 32;          // 16-row frags per wave in M
  __shared__ __align__(16) bf16 As[TM * 64];
  __shared__ __align__(16) bf16 Bs[128 * 64];
  const int nb = blockIdx.x * 128;
  const int mb = blockIdx.y * TM;
  const int t = threadIdx.x;
  const int wv = t >> 6;
  const int lane = t & 63;
  const int l16 = lane & 15;
  const int quad = lane >> 4;
  const int wm = (wv & 1) * (TM / 2);
  const int wn = (wv >> 1) * 64;

  const int trow = t >> 3;        // 0..31 (row within a 32-row chunk)
  const int tcol = (t & 7) * 8;   // element col within BK=64

  const f32x4 zero4 = {0.f, 0.f, 0.f, 0.f};
  f32x4 acc[MI][4];
#pragma unroll
  for (int i = 0; i < MI; ++i)
#pragma unroll
    for (int j = 0; j < 4; ++j) acc[i][j] = zero4;

  const bf16* ag = A + (size_t)(mb + trow) * DM_SZ + tcol;
  const bf16* bg = Wt + (size_t)(nb + trow) * DM_SZ + tcol;

  for (int k0 = 0; k0 < DM_SZ; k0 += 64) {
    __syncthreads();  // previous iteration's LDS reads complete
#pragma unroll
    for (int i = 0; i < MI; ++i)
      gload_lds16(ag + (size_t)i * 32 * DM_SZ + k0, As + i * 2048 + t * 8);
#pragma unroll
    for (int i = 0; i < 4; ++i)
      gload_lds16(bg + (size_t)i * 32 * DM_SZ + k0, Bs + i * 2048 + t * 8);
    __syncthreads();  // drains vmcnt before barrier -> staging visible
#pragma unroll
    for (int ks = 0; ks < 2; ++ks) {
      bf16x8 af[MI];
#pragma unroll
      for (int mi = 0; mi < MI; ++mi)
        af[mi] = *(const bf16x8*)(As + (wm + mi * 16 + l16) * 64 + ks * 32 + quad * 8);
#pragma unroll
      for (int ni = 0; ni < 4; ++ni) {
        bf16x8 bfr = *(const bf16x8*)(Bs + (wn + ni * 16 + l16) * 64 + ks * 32 + quad * 8);
#pragma unroll
        for (int mi = 0; mi < MI; ++mi)
          acc[mi][ni] = mfma_16x16x32(af[mi], bfr, acc[mi][ni]);
      }
    }
  }

  if (EPI == 0) {
    const int seg = nb >> 10;  // 0=q 1=k 2=v
    const int c0 = (nb & 1023) + wn;
    const float* bias = seg == 0 ? qb : seg == 1 ? kb : vb;
    bf16* outp = seg == 0 ? Qp : seg == 1 ? Kp : V;
#pragma unroll
    for (int ni = 0; ni < 4; ++ni) {
      const int col = c0 + ni * 16 + l16;
      const float bv = bias[col];
#pragma unroll
      for (int mi = 0; mi < MI; ++mi) {
#pragma unroll
        for (int r = 0; r < 4; ++r) {
          const int row = mb + wm + mi * 16 + quad * 4 + r;
          float v = acc[mi][ni][r] + bv;
          if (seg < 2) v = (v > 0.f) ? (v + 1.f) : __expf(v);
          outp[(size_t)row * DM_SZ + col] = (bf16)v;
        }
      }
    }
  } else {
#pragma unroll
    for (int ni = 0; ni < 4; ++ni) {
      const int col = nb + wn + ni * 16 + l16;
      const float bv = qb[col];  // ob passed via qb slot
#pragma unroll
      for (int mi = 0; mi < MI; ++mi) {
#pragma unroll
        for (int r = 0; r < 4; ++r) {
          const int row = mb + wm + mi * 16 + quad * 4 + r;
          outF[(size_t)row * DM_SZ + col] = acc[mi][ni][r] + bv;
        }
      }
    }
  }
}

// ---------------------------------------------------------------------------
// Logit GEMM: A(2048x1024) x lwT(192x1024) -> f32 logits. 128x64 tile.
// ---------------------------------------------------------------------------
__global__ __launch_bounds__(256) void k_gemm_logit(const bf16* __restrict__ A,
                                                    const bf16* __restrict__ Wt,
                                                    const float* __restrict__ lb,
                                                    float* __restrict__ logit) {
  __shared__ __align__(16) bf16 As[128][80];
  __shared__ __align__(16) bf16 Bs[64][80];
  const int nb = blockIdx.x * 64;
  const int mb = blockIdx.y * 128;
  const int t = threadIdx.x;
  const int wv = t >> 6;
  const int lane = t & 63;
  const int l16 = lane & 15;
  const int quad = lane >> 4;
  const int m0 = wv * 32;

  const int ar = t >> 1;
  const int ak = (t & 1) << 5;
  const int br = t >> 2;
  const int bk = (t & 3) << 4;

  const f32x4 zero4 = {0.f, 0.f, 0.f, 0.f};
  f32x4 acc[2][4];
#pragma unroll
  for (int i = 0; i < 2; ++i)
#pragma unroll
    for (int j = 0; j < 4; ++j) acc[i][j] = zero4;

  for (int k0 = 0; k0 < DM_SZ; k0 += 64) {
    const bf16* apg = A + (size_t)(mb + ar) * DM_SZ + k0 + ak;
    bf16x8 a0 = *(const bf16x8*)(apg);
    bf16x8 a1 = *(const bf16x8*)(apg + 8);
    bf16x8 a2 = *(const bf16x8*)(apg + 16);
    bf16x8 a3 = *(const bf16x8*)(apg + 24);
    const bf16* bpg = Wt + (size_t)(nb + br) * DM_SZ + k0 + bk;
    bf16x8 b0 = *(const bf16x8*)(bpg);
    bf16x8 b1 = *(const bf16x8*)(bpg + 8);
    __syncthreads();
    *(bf16x8*)&As[ar][ak] = a0;
    *(bf16x8*)&As[ar][ak + 8] = a1;
    *(bf16x8*)&As[ar][ak + 16] = a2;
    *(bf16x8*)&As[ar][ak + 24] = a3;
    *(bf16x8*)&Bs[br][bk] = b0;
    *(bf16x8*)&Bs[br][bk + 8] = b1;
    __syncthreads();
#pragma unroll
    for (int ks = 0; ks < 2; ++ks) {
      bf16x8 af0 = *(const bf16x8*)&As[m0 + l16][ks * 32 + quad * 8];
      bf16x8 af1 = *(const bf16x8*)&As[m0 + 16 + l16][ks * 32 + quad * 8];
#pragma unroll
      for (int tn = 0; tn < 4; ++tn) {
        bf16x8 bfr = *(const bf16x8*)&Bs[tn * 16 + l16][ks * 32 + quad * 8];
        acc[0][tn] = mfma_16x16x32(af0, bfr, acc[0][tn]);
        acc[1][tn] = mfma_16x16x32(af1, bfr, acc[1][tn]);
      }
    }
  }
#pragma unroll
  for (int mi = 0; mi < 2; ++mi) {
#pragma unroll
    for (int tn = 0; tn < 4; ++tn) {
      const int col = nb + tn * 16 + l16;
      const float bv = lb[col];
#pragma unroll
      for (int r = 0; r < 4; ++r) {
        const int row = mb + m0 + mi * 16 + quad * 4 + r;
        logit[(size_t)row * (H_SZ * L_SZ) + col] = acc[mi][tn][r] + bv;
      }
    }
  }
}

// ---------------------------------------------------------------------------
// Fenwick weighted causal linear attention + fused softmax-12 preamble.
// 1D grid 512 = 16 q-tiles x 32 (b,h), heavy-first balanced ordering.
// lvl(i,j) = 31 - clz((i+1) ^ j). Pl XOR-swizzled (conflict-free).
// ---------------------------------------------------------------------------
__global__ __launch_bounds__(256) void k_attn(const bf16* __restrict__ Qp,
                                              const bf16* __restrict__ Kp,
                                              const bf16* __restrict__ VTg,
                                              const float* __restrict__ Lg,
                                              bf16* __restrict__ O) {
  __shared__ __align__(16) bf16 Ks[64][80];
  __shared__ __align__(16) bf16 VTs[64][80];
  __shared__ __align__(16) bf16 Pl[4][16][80];
  __shared__ float Ws[64 * L_SZ];

  const int idx = blockIdx.x;
  const int s = idx >> 5;
  const int bh = idx & 31;
  const int it = (s < 8) ? (15 - s) : (s - 8);
  const int b = bh >> 4;
  const int h = bh & 15;
  const int i0 = it * 64;
  const int t = threadIdx.x;
  const int wv = t >> 6;
  const int lane = t & 63;
  const int l16 = lane & 15;
  const int quad = lane >> 4;
  const int m0 = wv * 16;

  const size_t base_bt = (size_t)b * T_SZ;

  const bf16* qptr = Qp + (base_bt + i0 + m0 + l16) * DM_SZ + h * 64 + quad * 8;
  const bf16x8 aq0 = *(const bf16x8*)(qptr);
  const bf16x8 aq1 = *(const bf16x8*)(qptr + 32);

  // fused softmax over raw logits for this block's 64 query rows
  if (t < 64) {
    const float* lp = Lg + (base_bt + i0 + t) * (H_SZ * L_SZ) + h * L_SZ;
    float v[L_SZ];
    float m = -1e30f;
#pragma unroll
    for (int l = 0; l < L_SZ; ++l) { v[l] = lp[l]; m = fmaxf(m, v[l]); }
    float sum = 0.f;
#pragma unroll
    for (int l = 0; l < L_SZ; ++l) { v[l] = __expf(v[l] - m); sum += v[l]; }
    const float inv = 1.f / sum;
#pragma unroll
    for (int l = 0; l < L_SZ; ++l) Ws[t * L_SZ + l] = v[l] * inv;
  }

  const f32x4 zero4 = {0.f, 0.f, 0.f, 0.f};
  f32x4 accn[4];
#pragma unroll
  for (int tn = 0; tn < 4; ++tn) accn[tn] = zero4;
  float den[4] = {0.f, 0.f, 0.f, 0.f};

  const int sr = t >> 2;
  const int sc = (t & 3) << 4;

  const bf16* vtrow = VTg + ((size_t)bh * 64 + sr) * T_SZ;

  for (int jt = 0; jt <= it; ++jt) {
    const int j0 = jt * 64;
    const bf16* kpg = Kp + (base_bt + j0 + sr) * DM_SZ + h * 64 + sc;
    bf16x8 k0v = *(const bf16x8*)(kpg);
    bf16x8 k1v = *(const bf16x8*)(kpg + 8);
    const bf16* vpg = vtrow + j0 + sc;
    bf16x8 v0v = *(const bf16x8*)(vpg);
    bf16x8 v1v = *(const bf16x8*)(vpg + 8);
    __syncthreads();
    *(bf16x8*)&Ks[sr][sc] = k0v;
    *(bf16x8*)&Ks[sr][sc + 8] = k1v;
    *(bf16x8*)&VTs[sr][sc] = v0v;
    *(bf16x8*)&VTs[sr][sc + 8] = v1v;
    __syncthreads();

    // S = Qp * Kp^T (16 x 64 per wave)
    f32x4 sacc[4];
#pragma unroll
    for (int tn = 0; tn < 4; ++tn) {
      sacc[tn] = zero4;
      bf16x8 bk0 = *(const bf16x8*)&Ks[tn * 16 + l16][quad * 8];
      bf16x8 bk1 = *(const bf16x8*)&Ks[tn * 16 + l16][32 + quad * 8];
      sacc[tn] = mfma_16x16x32(aq0, bk0, sacc[tn]);
      sacc[tn] = mfma_16x16x32(aq1, bk1, sacc[tn]);
    }

    // P = S * w[lvl(i,j)], causal; swizzled wave-private LDS store
#pragma unroll
    for (int tn = 0; tn < 4; ++tn) {
#pragma unroll
      for (int r = 0; r < 4; ++r) {
        const int il = m0 + quad * 4 + r;
        const int ig = i0 + il;
        const int jg = j0 + tn * 16 + l16;
        float p = 0.f;
        if (jg <= ig) {
          const int lvl = 31 - __clz((unsigned)((ig + 1) ^ jg));
          p = sacc[tn][r] * Ws[il * L_SZ + lvl];
        }
        den[r] += p;
        Pl[wv][quad * 4 + r][(tn * 16 + l16) ^ (quad << 4)] = (bf16)p;
      }
    }

    // num += P @ V
#pragma unroll
    for (int ks = 0; ks < 2; ++ks) {
      bf16x8 apf = *(const bf16x8*)&Pl[wv][l16][(ks * 32 + quad * 8) ^ ((l16 >> 2) << 4)];
#pragma unroll
      for (int tn = 0; tn < 4; ++tn) {
        bf16x8 bvf = *(const bf16x8*)&VTs[tn * 16 + l16][ks * 32 + quad * 8];
        accn[tn] = mfma_16x16x32(apf, bvf, accn[tn]);
      }
    }
  }

#pragma unroll
  for (int r = 0; r < 4; ++r) {
    float d = den[r];
    d += __shfl_xor(d, 1, 64);
    d += __shfl_xor(d, 2, 64);
    d += __shfl_xor(d, 4, 64);
    d += __shfl_xor(d, 8, 64);
    den[r] = fmaxf(d, 1e-6f);
  }

#pragma unroll
  for (int tn = 0; tn < 4; ++tn) {
#pragma unroll
    for (int r = 0; r < 4; ++r) {
      const int il = m0 + quad * 4 + r;
      O[(base_bt + i0 + il) * DM_SZ + h * 64 + tn * 16 + l16] =
          (bf16)(accn[tn][r] / den[r]);
    }
  }
}

// ---------------------------------------------------------------------------
extern "C" void kernel_launch(void* const* d_in, const int* in_sizes, int n_in,
                              void* d_out, int out_size, void* d_ws, size_t ws_size,
                              hipStream_t stream) {
  (void)in_sizes; (void)n_in; (void)out_size; (void)ws_size;
  const float* x  = (const float*)d_in[0];
  const float* qw = (const float*)d_in[1];
  const float* qb = (const float*)d_in[2];
  const float* kw = (const float*)d_in[3];
  const float* kb = (const float*)d_in[4];
  const float* vw = (const float*)d_in[5];
  const float* vb = (const float*)d_in[6];
  const float* lw = (const float*)d_in[7];
  const float* lb = (const float*)d_in[8];
  const float* ow = (const float*)d_in[9];
  const float* ob = (const float*)d_in[10];
  // d_in[11] = level_masks: unused — lvl(i,j) = 31 - clz((i+1)^j).

  char* ws = (char*)d_ws;
  size_t off = 0;
  auto alloc = [&](size_t bytes) -> char* {
    char* p = ws + off;
    off += (bytes + 255) & ~(size_t)255;
    return p;
  };
  bf16* xb     = (bf16*)alloc((size_t)M_ROWS * DM_SZ * 2);
  bf16* wqkvT  = (bf16*)alloc((size_t)N_QKV * DM_SZ * 2);
  bf16* lwT    = (bf16*)alloc((size_t)(H_SZ * L_SZ) * DM_SZ * 2);
  bf16* owT    = (bf16*)alloc((size_t)DM_SZ * DM_SZ * 2);
  bf16* Qp     = (bf16*)alloc((size_t)M_ROWS * DM_SZ * 2);
  bf16* Kpb    = (bf16*)alloc((size_t)M_ROWS * DM_SZ * 2);
  bf16* Vb     = (bf16*)alloc((size_t)M_ROWS * DM_SZ * 2);
  bf16* VTg    = (bf16*)alloc((size_t)M_ROWS * DM_SZ * 2);
  bf16* attn   = (bf16*)alloc((size_t)M_ROWS * DM_SZ * 2);
  float* logit = (float*)alloc((size_t)M_ROWS * H_SZ * L_SZ * 4);

  const dim3 blk(256);
  k_cast<<<dim3(M_ROWS * DM_SZ / 8 / 256), blk, 0, stream>>>(x, xb);
  k_transpose5<<<dim3(16, 16, 5), blk, 0, stream>>>(
      qw, wqkvT,
      kw, wqkvT + (size_t)1024 * DM_SZ,
      vw, wqkvT + (size_t)2048 * DM_SZ,
      ow, owT,
      lw, lwT);

  k_gemm128<128, 0><<<dim3(N_QKV / 128, M_ROWS / 128), blk, 0, stream>>>(
      xb, wqkvT, qb, kb, vb, Qp, Kpb, Vb, nullptr);
  k_gemm_logit<<<dim3(3, 16), blk, 0, stream>>>(xb, lwT, lb, logit);

  k_vtrans<<<dim3(T_SZ / 64, B_SZ * H_SZ), blk, 0, stream>>>(Vb, VTg);

  k_attn<<<dim3((T_SZ / 64) * B_SZ * H_SZ), blk, 0, stream>>>(Qp, Kpb, VTg, logit, attn);

  k_gemm128<64, 1><<<dim3(DM_SZ / 128, M_ROWS / 64), blk, 0, stream>>>(
      attn, owT, ob, nullptr, nullptr, nullptr, nullptr, nullptr, (float*)d_out);
}

// Round 5
// 181.398 us; speedup vs baseline: 1.2044x; 1.2044x over previous
//
#include <hip/hip_runtime.h>
#include <math.h>

typedef __bf16 bf16;
typedef __attribute__((ext_vector_type(4))) __bf16 bf16x4;
typedef __attribute__((ext_vector_type(8))) __bf16 bf16x8;
typedef __attribute__((ext_vector_type(4))) float f32x4;

#define B_SZ 2
#define T_SZ 1024
#define DM_SZ 1024
#define H_SZ 16
#define D_SZ 64
#define L_SZ 12
#define M_ROWS 2048      // B*T
#define N_PAD 3328       // q(1024)+k(1024)+v(1024)+logit(192)+pad(64)

__device__ __forceinline__ f32x4 mfma_16x16x32(bf16x8 a, bf16x8 b, f32x4 c) {
  return __builtin_amdgcn_mfma_f32_16x16x32_bf16(a, b, c, 0, 0, 0);
}

// async global->LDS, 16B/lane; LDS dest = wave-uniform base + lane*16.
__device__ __forceinline__ void gload_lds16(const bf16* g, bf16* l) {
  __builtin_amdgcn_global_load_lds((const __attribute__((address_space(1))) void*)g,
                                   (__attribute__((address_space(3))) void*)l,
                                   16, 0, 0);
}

// ---------------------------------------------------------------------------
// Prep: z=0..3 weight transposes (1024x1024), z=4 lw transpose (1024x192),
// z=5 x fp32->bf16 cast. Grid (16,16,6), block 256.
// ---------------------------------------------------------------------------
__global__ __launch_bounds__(256) void k_prep(
    const float* __restrict__ x, bf16* __restrict__ xb,
    const float* __restrict__ qw, const float* __restrict__ kw,
    const float* __restrict__ vw, const float* __restrict__ ow,
    const float* __restrict__ lw,
    bf16* __restrict__ wqkvT, bf16* __restrict__ owT) {
  const int z = blockIdx.z;
  const int t = threadIdx.x;
  if (z == 5) {  // cast 2048x1024 fp32 -> bf16, 8192 els per block
    const size_t base = ((size_t)blockIdx.y * 16 + blockIdx.x) * 8192 + t * 32;
#pragma unroll
    for (int u = 0; u < 4; ++u) {
      const float* p = x + base + u * 8;
      f32x4 a = *(const f32x4*)p;
      f32x4 b = *(const f32x4*)(p + 4);
      bf16x8 o;
#pragma unroll
      for (int e = 0; e < 4; ++e) { o[e] = (bf16)a[e]; o[e + 4] = (bf16)b[e]; }
      *(bf16x8*)(xb + base + u * 8) = o;
    }
    return;
  }
  __shared__ __align__(16) bf16 tile[64][66];
  const float* in; bf16* out; int C = 1024;
  if (z == 0)      { in = qw; out = wqkvT; }
  else if (z == 1) { in = kw; out = wqkvT + (size_t)1024 * DM_SZ; }
  else if (z == 2) { in = vw; out = wqkvT + (size_t)2048 * DM_SZ; }
  else if (z == 3) { in = ow; out = owT; }
  else             { in = lw; out = wqkvT + (size_t)3072 * DM_SZ; C = 192;
                     if (blockIdx.x >= 3) return; }
  const int tc = blockIdx.x * 64;
  const int tr = blockIdx.y * 64;
  const int r = t >> 2;
  const int c4 = (t & 3) << 4;
  const float* src = in + (size_t)(tr + r) * C + tc + c4;
  f32x4 f0 = *(const f32x4*)(src);
  f32x4 f1 = *(const f32x4*)(src + 4);
  f32x4 f2 = *(const f32x4*)(src + 8);
  f32x4 f3 = *(const f32x4*)(src + 12);
#pragma unroll
  for (int e = 0; e < 4; ++e) {
    tile[r][c4 + e]      = (bf16)f0[e];
    tile[r][c4 + 4 + e]  = (bf16)f1[e];
    tile[r][c4 + 8 + e]  = (bf16)f2[e];
    tile[r][c4 + 12 + e] = (bf16)f3[e];
  }
  __syncthreads();
  bf16x8 w0, w1;
#pragma unroll
  for (int e = 0; e < 8; ++e) { w0[e] = tile[c4 + e][r]; w1[e] = tile[c4 + 8 + e][r]; }
  bf16* dst = out + (size_t)(tc + r) * DM_SZ + tr + c4;
  *(bf16x8*)(dst) = w0;
  *(bf16x8*)(dst + 8) = w1;
}

// ---------------------------------------------------------------------------
// Fused QKVL GEMM: xb(2048x1024) x wqkvT(3328x1024) -> Qp/Kp (phi, bf16),
// VTg (plain, transposed in epilogue), logit (f32, raw). Tile 128x128, BK=64.
// ---------------------------------------------------------------------------
__global__ __launch_bounds__(256) void k_gemm_qkvl(
    const bf16* __restrict__ A, const bf16* __restrict__ Wt,
    const float* __restrict__ qb, const float* __restrict__ kb,
    const float* __restrict__ vb, const float* __restrict__ lb,
    bf16* __restrict__ Qp, bf16* __restrict__ Kp,
    bf16* __restrict__ VTg, float* __restrict__ logit) {
  __shared__ __align__(16) char smem[34816];  // As|Bs (32KB) / Trt (34KB)
  bf16* As = (bf16*)smem;
  bf16* Bs = As + 8192;
  const int nb = blockIdx.x * 128;
  const int mb = blockIdx.y * 128;
  const int t = threadIdx.x;
  const int wv = t >> 6;
  const int lane = t & 63;
  const int l16 = lane & 15;
  const int quad = lane >> 4;
  const int wm = (wv & 1) * 64;
  const int wn = (wv >> 1) * 64;

  const int trow = t >> 3;        // 0..31
  const int tcol = (t & 7) * 8;

  const f32x4 zero4 = {0.f, 0.f, 0.f, 0.f};
  f32x4 acc[4][4];
#pragma unroll
  for (int i = 0; i < 4; ++i)
#pragma unroll
    for (int j = 0; j < 4; ++j) acc[i][j] = zero4;

  const bf16* ag = A + (size_t)(mb + trow) * DM_SZ + tcol;
  const bf16* bg = Wt + (size_t)(nb + trow) * DM_SZ + tcol;

  for (int k0 = 0; k0 < DM_SZ; k0 += 64) {
    __syncthreads();
#pragma unroll
    for (int i = 0; i < 4; ++i)
      gload_lds16(ag + (size_t)i * 32 * DM_SZ + k0, As + i * 2048 + t * 8);
#pragma unroll
    for (int i = 0; i < 4; ++i)
      gload_lds16(bg + (size_t)i * 32 * DM_SZ + k0, Bs + i * 2048 + t * 8);
    __syncthreads();
#pragma unroll
    for (int ks = 0; ks < 2; ++ks) {
      bf16x8 af[4];
#pragma unroll
      for (int mi = 0; mi < 4; ++mi)
        af[mi] = *(const bf16x8*)(As + (wm + mi * 16 + l16) * 64 + ks * 32 + quad * 8);
#pragma unroll
      for (int ni = 0; ni < 4; ++ni) {
        bf16x8 bfr = *(const bf16x8*)(Bs + (wn + ni * 16 + l16) * 64 + ks * 32 + quad * 8);
#pragma unroll
        for (int mi = 0; mi < 4; ++mi)
          acc[mi][ni] = mfma_16x16x32(af[mi], bfr, acc[mi][ni]);
      }
    }
  }

  const int seg = nb >> 10;  // 0=q 1=k 2=v 3=logit
  if (seg < 2) {
    const float* bias = seg == 0 ? qb : kb;
    bf16* outp = seg == 0 ? Qp : Kp;
    const int c0 = (nb & 1023) + wn;
#pragma unroll
    for (int ni = 0; ni < 4; ++ni) {
      const int col = c0 + ni * 16 + l16;
      const float bv = bias[col];
#pragma unroll
      for (int mi = 0; mi < 4; ++mi) {
#pragma unroll
        for (int r = 0; r < 4; ++r) {
          const int row = mb + wm + mi * 16 + quad * 4 + r;
          float v = acc[mi][ni][r] + bv;
          v = (v > 0.f) ? (v + 1.f) : __expf(v);
          outp[(size_t)row * DM_SZ + col] = (bf16)v;
        }
      }
    }
  } else if (seg == 2) {
    // V: bias, transpose via LDS (stride 136), store VTg[b*1024+d][t]
    bf16* Trt = (bf16*)smem;
    const int cb = nb - 2048;
    __syncthreads();  // K-loop LDS frag reads complete before overwrite
#pragma unroll
    for (int ni = 0; ni < 4; ++ni) {
      const int nloc = wn + ni * 16 + l16;
      const float bv = vb[cb + nloc];
#pragma unroll
      for (int mi = 0; mi < 4; ++mi) {
        const int mloc = wm + mi * 16 + quad * 4;
        bf16x4 pk;
#pragma unroll
        for (int r = 0; r < 4; ++r) pk[r] = (bf16)(acc[mi][ni][r] + bv);
        *(bf16x4*)&Trt[nloc * 136 + mloc] = pk;
      }
    }
    __syncthreads();
    const int dn = t >> 1, ch = t & 1;
    const int bq = mb >> 10;
    const int m0g = mb & 1023;
    bf16* dst = VTg + ((size_t)(bq * 1024 + cb + dn)) * T_SZ + m0g + ch * 64;
    const bf16* srcl = Trt + dn * 136 + ch * 64;
#pragma unroll
    for (int e = 0; e < 8; ++e)
      *(bf16x8*)(dst + e * 8) = *(const bf16x8*)(srcl + e * 8);
  } else {
    const int lc0 = (nb - 3072) + wn;
#pragma unroll
    for (int ni = 0; ni < 4; ++ni) {
      const int lcol = lc0 + ni * 16 + l16;
      if (lcol < H_SZ * L_SZ) {
        const float bv = lb[lcol];
#pragma unroll
        for (int mi = 0; mi < 4; ++mi) {
#pragma unroll
          for (int r = 0; r < 4; ++r) {
            const int row = mb + wm + mi * 16 + quad * 4 + r;
            logit[(size_t)row * (H_SZ * L_SZ) + lcol] = acc[mi][ni][r] + bv;
          }
        }
      }
    }
  }
}

// ---------------------------------------------------------------------------
// Fenwick weighted causal linear attention + fused softmax-12.
// Off-diagonal tiles (jt<it): level constant per row — lvl=6+fls(it^jt)
// (row 63: 6+fls((it+1)^jt)); no clz/mask per element.
// ---------------------------------------------------------------------------
__global__ __launch_bounds__(256) void k_attn(const bf16* __restrict__ Qp,
                                              const bf16* __restrict__ Kp,
                                              const bf16* __restrict__ VTg,
                                              const float* __restrict__ Lg,
                                              bf16* __restrict__ O) {
  __shared__ __align__(16) bf16 Ks[64][80];
  __shared__ __align__(16) bf16 VTs[64][80];
  __shared__ __align__(16) bf16 Pl[4][16][80];
  __shared__ float Ws[64 * L_SZ];

  const int idx = blockIdx.x;
  const int s = idx >> 5;
  const int bh = idx & 31;
  const int it = (s < 8) ? (15 - s) : (s - 8);  // heavy-first balance
  const int b = bh >> 4;
  const int h = bh & 15;
  const int i0 = it * 64;
  const int t = threadIdx.x;
  const int wv = t >> 6;
  const int lane = t & 63;
  const int l16 = lane & 15;
  const int quad = lane >> 4;
  const int m0 = wv * 16;

  const size_t base_bt = (size_t)b * T_SZ;

  const bf16* qptr = Qp + (base_bt + i0 + m0 + l16) * DM_SZ + h * 64 + quad * 8;
  const bf16x8 aq0 = *(const bf16x8*)(qptr);
  const bf16x8 aq1 = *(const bf16x8*)(qptr + 32);

  if (t < 64) {  // fused softmax for this block's 64 query rows
    const float* lp = Lg + (base_bt + i0 + t) * (H_SZ * L_SZ) + h * L_SZ;
    float v[L_SZ];
    float m = -1e30f;
#pragma unroll
    for (int l = 0; l < L_SZ; ++l) { v[l] = lp[l]; m = fmaxf(m, v[l]); }
    float sum = 0.f;
#pragma unroll
    for (int l = 0; l < L_SZ; ++l) { v[l] = __expf(v[l] - m); sum += v[l]; }
    const float inv = 1.f / sum;
#pragma unroll
    for (int l = 0; l < L_SZ; ++l) Ws[t * L_SZ + l] = v[l] * inv;
  }

  const f32x4 zero4 = {0.f, 0.f, 0.f, 0.f};
  f32x4 accn[4];
#pragma unroll
  for (int tn = 0; tn < 4; ++tn) accn[tn] = zero4;
  float den[4] = {0.f, 0.f, 0.f, 0.f};

  const int sr = t >> 2;
  const int sc = (t & 3) << 4;
  const int il_base = m0 + quad * 4;

  const bf16* vtrow = VTg + ((size_t)bh * 64 + sr) * T_SZ;

  for (int jt = 0; jt <= it; ++jt) {
    const int j0 = jt * 64;
    const bf16* kpg = Kp + (base_bt + j0 + sr) * DM_SZ + h * 64 + sc;
    bf16x8 k0v = *(const bf16x8*)(kpg);
    bf16x8 k1v = *(const bf16x8*)(kpg + 8);
    const bf16* vpg = vtrow + j0 + sc;
    bf16x8 v0v = *(const bf16x8*)(vpg);
    bf16x8 v1v = *(const bf16x8*)(vpg + 8);
    __syncthreads();
    *(bf16x8*)&Ks[sr][sc] = k0v;
    *(bf16x8*)&Ks[sr][sc + 8] = k1v;
    *(bf16x8*)&VTs[sr][sc] = v0v;
    *(bf16x8*)&VTs[sr][sc + 8] = v1v;
    __syncthreads();

    // S = Qp * Kp^T (16 x 64 per wave)
    f32x4 sacc[4];
#pragma unroll
    for (int tn = 0; tn < 4; ++tn) {
      sacc[tn] = zero4;
      bf16x8 bk0 = *(const bf16x8*)&Ks[tn * 16 + l16][quad * 8];
      bf16x8 bk1 = *(const bf16x8*)&Ks[tn * 16 + l16][32 + quad * 8];
      sacc[tn] = mfma_16x16x32(aq0, bk0, sacc[tn]);
      sacc[tn] = mfma_16x16x32(aq1, bk1, sacc[tn]);
    }

    if (jt < it) {
      // level constant per row across this tile
      const int lvlA = 6 + (31 - __clz((unsigned)(it ^ jt)));
      const int lvlB = 6 + (31 - __clz((unsigned)((it + 1) ^ jt)));
      float wrow[4];
#pragma unroll
      for (int r = 0; r < 4; ++r) {
        const int il = il_base + r;
        wrow[r] = Ws[il * L_SZ + ((il == 63) ? lvlB : lvlA)];
      }
#pragma unroll
      for (int tn = 0; tn < 4; ++tn) {
#pragma unroll
        for (int r = 0; r < 4; ++r) {
          const float p = sacc[tn][r] * wrow[r];
          den[r] += p;
          Pl[wv][quad * 4 + r][(tn * 16 + l16) ^ (quad << 4)] = (bf16)p;
        }
      }
    } else {
      // diagonal tile: exact per-element level + causal mask
#pragma unroll
      for (int tn = 0; tn < 4; ++tn) {
#pragma unroll
        for (int r = 0; r < 4; ++r) {
          const int il = il_base + r;
          const int ig = i0 + il;
          const int jg = j0 + tn * 16 + l16;
          float p = 0.f;
          if (jg <= ig) {
            const int lvl = 31 - __clz((unsigned)((ig + 1) ^ jg));
            p = sacc[tn][r] * Ws[il * L_SZ + lvl];
          }
          den[r] += p;
          Pl[wv][quad * 4 + r][(tn * 16 + l16) ^ (quad << 4)] = (bf16)p;
        }
      }
    }

    // num += P @ V
#pragma unroll
    for (int ks = 0; ks < 2; ++ks) {
      bf16x8 apf = *(const bf16x8*)&Pl[wv][l16][(ks * 32 + quad * 8) ^ ((l16 >> 2) << 4)];
#pragma unroll
      for (int tn = 0; tn < 4; ++tn) {
        bf16x8 bvf = *(const bf16x8*)&VTs[tn * 16 + l16][ks * 32 + quad * 8];
        accn[tn] = mfma_16x16x32(apf, bvf, accn[tn]);
      }
    }
  }

#pragma unroll
  for (int r = 0; r < 4; ++r) {
    float d = den[r];
    d += __shfl_xor(d, 1, 64);
    d += __shfl_xor(d, 2, 64);
    d += __shfl_xor(d, 4, 64);
    d += __shfl_xor(d, 8, 64);
    den[r] = fmaxf(d, 1e-6f);
  }

#pragma unroll
  for (int tn = 0; tn < 4; ++tn) {
#pragma unroll
    for (int r = 0; r < 4; ++r) {
      const int il = il_base + r;
      O[(base_bt + i0 + il) * DM_SZ + h * 64 + tn * 16 + l16] =
          (bf16)(accn[tn][r] / den[r]);
    }
  }
}

// ---------------------------------------------------------------------------
// Output GEMM: attn(2048x1024) x owT(1024x1024) + ob -> f32 out.
// Tile 64x64, grid (16,32)=512 blocks, global_load_lds staging.
// ---------------------------------------------------------------------------
__global__ __launch_bounds__(256) void k_gemm_out(const bf16* __restrict__ A,
                                                  const bf16* __restrict__ Wt,
                                                  const float* __restrict__ ob,
                                                  float* __restrict__ out) {
  __shared__ __align__(16) bf16 As[64 * 64];
  __shared__ __align__(16) bf16 Bs[64 * 64];
  const int nb = blockIdx.x * 64;
  const int mb = blockIdx.y * 64;
  const int t = threadIdx.x;
  const int wv = t >> 6;
  const int lane = t & 63;
  const int l16 = lane & 15;
  const int quad = lane >> 4;
  const int wm = wv * 16;

  const int trow = t >> 3;
  const int tcol = (t & 7) * 8;

  const f32x4 zero4 = {0.f, 0.f, 0.f, 0.f};
  f32x4 acc[4];
#pragma unroll
  for (int j = 0; j < 4; ++j) acc[j] = zero4;

  const bf16* ag = A + (size_t)(mb + trow) * DM_SZ + tcol;
  const bf16* bg = Wt + (size_t)(nb + trow) * DM_SZ + tcol;

  for (int k0 = 0; k0 < DM_SZ; k0 += 64) {
    __syncthreads();
    gload_lds16(ag + k0, As + t * 8);
    gload_lds16(ag + (size_t)32 * DM_SZ + k0, As + 2048 + t * 8);
    gload_lds16(bg + k0, Bs + t * 8);
    gload_lds16(bg + (size_t)32 * DM_SZ + k0, Bs + 2048 + t * 8);
    __syncthreads();
#pragma unroll
    for (int ks = 0; ks < 2; ++ks) {
      bf16x8 af = *(const bf16x8*)(As + (wm + l16) * 64 + ks * 32 + quad * 8);
#pragma unroll
      for (int ni = 0; ni < 4; ++ni) {
        bf16x8 bfr = *(const bf16x8*)(Bs + (ni * 16 + l16) * 64 + ks * 32 + quad * 8);
        acc[ni] = mfma_16x16x32(af, bfr, acc[ni]);
      }
    }
  }
#pragma unroll
  for (int ni = 0; ni < 4; ++ni) {
    const int col = nb + ni * 16 + l16;
    const float bv = ob[col];
#pragma unroll
    for (int r = 0; r < 4; ++r) {
      const int row = mb + wm + quad * 4 + r;
      out[(size_t)row * DM_SZ + col] = acc[ni][r] + bv;
    }
  }
}

// ---------------------------------------------------------------------------
extern "C" void kernel_launch(void* const* d_in, const int* in_sizes, int n_in,
                              void* d_out, int out_size, void* d_ws, size_t ws_size,
                              hipStream_t stream) {
  (void)in_sizes; (void)n_in; (void)out_size; (void)ws_size;
  const float* x  = (const float*)d_in[0];
  const float* qw = (const float*)d_in[1];
  const float* qb = (const float*)d_in[2];
  const float* kw = (const float*)d_in[3];
  const float* kb = (const float*)d_in[4];
  const float* vw = (const float*)d_in[5];
  const float* vb = (const float*)d_in[6];
  const float* lw = (const float*)d_in[7];
  const float* lb = (const float*)d_in[8];
  const float* ow = (const float*)d_in[9];
  const float* ob = (const float*)d_in[10];
  // d_in[11] = level_masks: unused — lvl(i,j) = 31 - clz((i+1)^j).

  char* ws = (char*)d_ws;
  size_t off = 0;
  auto alloc = [&](size_t bytes) -> char* {
    char* p = ws + off;
    off += (bytes + 255) & ~(size_t)255;
    return p;
  };
  bf16* xb     = (bf16*)alloc((size_t)M_ROWS * DM_SZ * 2);
  bf16* wqkvT  = (bf16*)alloc((size_t)N_PAD * DM_SZ * 2);  // rows 3264..3327 garbage (harmless)
  bf16* owT    = (bf16*)alloc((size_t)DM_SZ * DM_SZ * 2);
  bf16* Qp     = (bf16*)alloc((size_t)M_ROWS * DM_SZ * 2);
  bf16* Kpb    = (bf16*)alloc((size_t)M_ROWS * DM_SZ * 2);
  bf16* VTg    = (bf16*)alloc((size_t)M_ROWS * DM_SZ * 2);
  bf16* attn   = (bf16*)alloc((size_t)M_ROWS * DM_SZ * 2);
  float* logit = (float*)alloc((size_t)M_ROWS * H_SZ * L_SZ * 4);

  const dim3 blk(256);
  k_prep<<<dim3(16, 16, 6), blk, 0, stream>>>(x, xb, qw, kw, vw, ow, lw, wqkvT, owT);
  k_gemm_qkvl<<<dim3(N_PAD / 128, M_ROWS / 128), blk, 0, stream>>>(
      xb, wqkvT, qb, kb, vb, lb, Qp, Kpb, VTg, logit);
  k_attn<<<dim3((T_SZ / 64) * B_SZ * H_SZ), blk, 0, stream>>>(Qp, Kpb, VTg, logit, attn);
  k_gemm_out<<<dim3(DM_SZ / 64, M_ROWS / 64), blk, 0, stream>>>(attn, owT, ob, (float*)d_out);
}